// Round 2
// baseline (503.585 us; speedup 1.0000x reference)
//
#include <hip/hip_runtime.h>
#include <hip/hip_bf16.h>

typedef __attribute__((ext_vector_type(8))) short bf16x8;
typedef __attribute__((ext_vector_type(4))) float f32x4;
typedef __attribute__((ext_vector_type(4))) unsigned short u16x4;
typedef unsigned short US;

__device__ __forceinline__ f32x4 mfma16(bf16x8 a, bf16x8 b, f32x4 c) {
  return __builtin_amdgcn_mfma_f32_16x16x32_bf16(a, b, c, 0, 0, 0);
}

__device__ __forceinline__ US f2bf(float f) {
  union { float f; unsigned u; } x; x.f = f;
  unsigned r = x.u + 0x7fffu + ((x.u >> 16) & 1u);
  return (US)(r >> 16);
}

// async global->LDS, 16B per lane; LDS dest = wave-uniform base + lane*16
__device__ __forceinline__ void gld16(const US* gp, US* lp) {
  __builtin_amdgcn_global_load_lds(
      (const __attribute__((address_space(1))) unsigned*)gp,
      (__attribute__((address_space(3))) unsigned*)lp, 16, 0, 0);
}

// row remap fusing the time-concat: mode1: r=b*768+s -> b*1024+s ; mode2: r=b*256+s -> b*1024+768+s
__device__ __forceinline__ int map_row(int r, int mode) {
  if (mode == 1) { int b = r / 768; return b * 1024 + (r - b * 768); }
  if (mode == 2) { int b = r >> 8; return b * 1024 + 768 + (r & 255); }
  return r;
}

// ----------------- fp32 -> bf16 cast -----------------
__global__ void k_cast(const float* __restrict__ src, US* __restrict__ dst, int n4) {
  int i = blockIdx.x * 256 + threadIdx.x;
  if (i >= n4) return;
  f32x4 v = *reinterpret_cast<const f32x4*>(src + (size_t)i * 4);
  u16x4 o;
  o[0] = f2bf(v[0]); o[1] = f2bf(v[1]); o[2] = f2bf(v[2]); o[3] = f2bf(v[3]);
  *reinterpret_cast<u16x4*>(dst + (size_t)i * 4) = o;
}

// ------- batched transpose-pack: fp32 src[R][C] -> bf16 dst[C][R] -------
__global__ __launch_bounds__(256)
void k_tpack(const float* __restrict__ src, US* __restrict__ dst,
             int R, int C, long sbs, long dbs) {
  __shared__ float tile[32][33];
  int c0 = blockIdx.x * 32, r0 = blockIdx.y * 32;
  src += (long)blockIdx.z * sbs;
  dst += (long)blockIdx.z * dbs;
  int tx = threadIdx.x, ty = threadIdx.y;
#pragma unroll
  for (int i = 0; i < 4; ++i)
    tile[ty + 8 * i][tx] = src[(size_t)(r0 + ty + 8 * i) * C + c0 + tx];
  __syncthreads();
#pragma unroll
  for (int i = 0; i < 4; ++i)
    dst[(size_t)(c0 + ty + 8 * i) * R + r0 + tx] = f2bf(tile[tx][ty + 8 * i]);
}

// ------- bf16 GEMM: C[M,N] = A[M,K] * BT[N,K]^T, fp32 out, 128x128x32 tile -------
// m97 structure: global_load_lds width=16 staging, linear LDS, 2 barriers/K-step
template <int AMAP, int CMAP>
__global__ __launch_bounds__(256, 2)
void k_gemm(const US* __restrict__ A, const US* __restrict__ BT, float* __restrict__ C,
            int M, int N, int K) {
  __shared__ __align__(16) US lA[128 * 32];
  __shared__ __align__(16) US lB[128 * 32];
  const int tid = threadIdx.x;
  const int lane = tid & 63;
  const int wid = tid >> 6;
  const int wm = wid >> 1, wn = wid & 1;
  const int m0 = blockIdx.y * 128, n0 = blockIdx.x * 128;
  const int g = lane >> 4, c = lane & 15;

  // staging addresses: lane covers row (base + lane/4), 16B at col (lane&3)*8
  const int lrow = lane >> 2;
  const int lcol = (lane & 3) * 8;
  const size_t ga0 = (size_t)map_row(m0 + wid * 16 + lrow, AMAP) * K + lcol;
  const size_t ga1 = (size_t)map_row(m0 + 64 + wid * 16 + lrow, AMAP) * K + lcol;
  const size_t gb0 = (size_t)(n0 + wid * 16 + lrow) * K + lcol;
  const size_t gb1 = (size_t)(n0 + 64 + wid * 16 + lrow) * K + lcol;
  US* ldA0 = &lA[(wid * 16) * 32];
  US* ldA1 = &lA[(64 + wid * 16) * 32];
  US* ldB0 = &lB[(wid * 16) * 32];
  US* ldB1 = &lB[(64 + wid * 16) * 32];

  f32x4 acc[4][4];
#pragma unroll
  for (int i = 0; i < 4; ++i)
#pragma unroll
    for (int j = 0; j < 4; ++j) acc[i][j] = f32x4{0.f, 0.f, 0.f, 0.f};

  for (int k0 = 0; k0 < K; k0 += 32) {
    __syncthreads();  // previous iter's reads done before overwrite
    gld16(A + ga0 + k0, ldA0);
    gld16(A + ga1 + k0, ldA1);
    gld16(BT + gb0 + k0, ldB0);
    gld16(BT + gb1 + k0, ldB1);
    __syncthreads();  // compiler drains vmcnt(0) before barrier -> LDS ready
    bf16x8 af[4], bfr[4];
#pragma unroll
    for (int i = 0; i < 4; ++i) {
      af[i] = *reinterpret_cast<const bf16x8*>(&lA[(wm * 64 + i * 16 + c) * 32 + g * 8]);
      bfr[i] = *reinterpret_cast<const bf16x8*>(&lB[(wn * 64 + i * 16 + c) * 32 + g * 8]);
    }
#pragma unroll
    for (int i = 0; i < 4; ++i)
#pragma unroll
      for (int j = 0; j < 4; ++j)
        acc[i][j] = mfma16(af[i], bfr[j], acc[i][j]);
  }
#pragma unroll
  for (int i = 0; i < 4; ++i) {
#pragma unroll
    for (int r = 0; r < 4; ++r) {
      int orow = map_row(m0 + wm * 64 + i * 16 + 4 * g + r, CMAP);
      float* cp = C + (size_t)orow * N + n0 + wn * 64 + c;
#pragma unroll
      for (int j = 0; j < 4; ++j) cp[j * 16] = acc[i][j][r];
    }
  }
}

// ------- RoPE: q_raw(f32)->q_bf (roped*scale), kv_raw k-part -> k_bf + k_out(f32) -------
__global__ __launch_bounds__(256)
void k_rope(const float* __restrict__ q_raw, const float* __restrict__ kv_raw,
            const int* __restrict__ pos, US* __restrict__ q_bf,
            US* __restrict__ k_bf, float* __restrict__ k_out) {
  __shared__ float sa[128], ca[128];
  const int bt = blockIdx.x;
  const int tid = threadIdx.x;
  const int p = pos[bt];
  if (tid < 128) {
    float inv_ts = powf(10000.0f, -(float)tid * (1.0f / 128.0f));
    float r = (float)p * inv_ts;
    sa[tid] = sinf(r);
    ca[tid] = cosf(r);
  }
  __syncthreads();
  const float scale = 0.0625f;  // 256^-0.5
  const size_t qo = (size_t)bt * 2048;
#pragma unroll
  for (int it = 0; it < 4; ++it) {
    int idx = it * 256 + tid;
    int n = idx >> 7, j = idx & 127;
    float x1 = q_raw[qo + n * 256 + j];
    float x2 = q_raw[qo + n * 256 + j + 128];
    float s = sa[j], co = ca[j];
    q_bf[qo + n * 256 + j] = f2bf(scale * (x1 * co - x2 * s));
    q_bf[qo + n * 256 + j + 128] = f2bf(scale * (x2 * co + x1 * s));
  }
  if (tid < 128) {
    int j = tid;
    const size_t ko = (size_t)bt * 512;
    float x1 = kv_raw[ko + j], x2 = kv_raw[ko + j + 128];
    float s = sa[j], co = ca[j];
    float o1 = x1 * co - x2 * s, o2 = x2 * co + x1 * s;
    const size_t kd = (size_t)bt * 256;
    k_bf[kd + j] = f2bf(o1);
    k_bf[kd + j + 128] = f2bf(o2);
    k_out[kd + j] = o1;
    k_out[kd + j + 128] = o2;
  }
}

// ------- V: kv_raw v-part -> v_out(f32) + vt bf16 [b][h][t] -------
__global__ __launch_bounds__(256)
void k_vtrans(const float* __restrict__ kv_raw, float* __restrict__ v_out, US* __restrict__ vt) {
  __shared__ float tile[32][33];
  int t0 = blockIdx.x * 32, h0 = blockIdx.y * 32, b = blockIdx.z;
  int tx = threadIdx.x, ty = threadIdx.y;
#pragma unroll
  for (int i = 0; i < 4; ++i) {
    int t = t0 + ty + 8 * i;
    float v = kv_raw[(size_t)(b * 1024 + t) * 512 + 256 + h0 + tx];
    tile[ty + 8 * i][tx] = v;
    v_out[(size_t)(b * 1024 + t) * 256 + h0 + tx] = v;
  }
  __syncthreads();
#pragma unroll
  for (int i = 0; i < 4; ++i) {
    int h = h0 + ty + 8 * i;
    vt[(size_t)(b * 256 + h) * 1024 + t0 + tx] = f2bf(tile[tx][ty + 8 * i]);
  }
}

// ------- flash attention: 4-wave block, 4-way KV split + LDS merge -------
// wave w processes KV chunks c0 = 32*w, 32*w+128, ... (private m,l,acc);
// merge once per block via 16KB LDS. qt reversed for LPT scheduling.
__global__ __launch_bounds__(256, 4)
void k_attn(const US* __restrict__ qb, const US* __restrict__ kb,
            const US* __restrict__ vt, US* __restrict__ enc) {
  __shared__ float rbuf[16 * 256];
  __shared__ float sml[4][2][16];
  const int qt = 63 - blockIdx.x, n = blockIdx.y, b = blockIdx.z;
  const int tid = threadIdx.x;
  const int wid = tid >> 6;
  const int lane = tid & 63;
  const int g = lane >> 4, c = lane & 15;
  const int qbase = qt * 16;
  bf16x8 qf[8];
  {
    const US* qp = qb + ((size_t)((b * 1024 + qbase + c) * 8 + n)) * 256 + 8 * g;
#pragma unroll
    for (int ch = 0; ch < 8; ++ch)
      qf[ch] = *reinterpret_cast<const bf16x8*>(qp + ch * 32);
  }
  f32x4 acc[16];
#pragma unroll
  for (int i = 0; i < 16; ++i) acc[i] = f32x4{0.f, 0.f, 0.f, 0.f};
  float m_run = -3.0e38f, l_run = 0.f;
  const US* kbb = kb + (size_t)b * 262144 + (size_t)c * 256 + 8 * g;
  const US* vbb = vt + (size_t)b * 262144 + 8 * g;

  for (int c0 = 32 * wid; c0 <= qbase; c0 += 128) {
    const bool hb = (c0 + 16 <= qbase);
    f32x4 sA = {0.f, 0.f, 0.f, 0.f}, sB = {0.f, 0.f, 0.f, 0.f};
    const US* ka = kbb + (size_t)c0 * 256;
#pragma unroll
    for (int ch = 0; ch < 8; ++ch)
      sA = mfma16(*reinterpret_cast<const bf16x8*>(ka + ch * 32), qf[ch], sA);
    if (hb) {
      const US* ka2 = ka + 16 * 256;
#pragma unroll
      for (int ch = 0; ch < 8; ++ch)
        sB = mfma16(*reinterpret_cast<const bf16x8*>(ka2 + ch * 32), qf[ch], sB);
    }
    // causal mask on diagonal tiles: kv-row (4g+r) > q-row c
    if (c0 == qbase) {
#pragma unroll
      for (int r = 0; r < 4; ++r)
        if (4 * g + r > c) sA[r] = -3.0e38f;
    }
    if (hb && (c0 + 16 == qbase)) {
#pragma unroll
      for (int r = 0; r < 4; ++r)
        if (4 * g + r > c) sB[r] = -3.0e38f;
    }
    // per-q-row (column c) online softmax
    float tm = fmaxf(fmaxf(sA[0], sA[1]), fmaxf(sA[2], sA[3]));
    if (hb) tm = fmaxf(tm, fmaxf(fmaxf(sB[0], sB[1]), fmaxf(sB[2], sB[3])));
    tm = fmaxf(tm, __shfl_xor(tm, 16));
    tm = fmaxf(tm, __shfl_xor(tm, 32));
    const float m_new = fmaxf(m_run, tm);
    const float alpha = __expf(m_run - m_new);
    float pA[4], pB[4];
    float ls = 0.f;
#pragma unroll
    for (int r = 0; r < 4; ++r) { pA[r] = __expf(sA[r] - m_new); ls += pA[r]; }
#pragma unroll
    for (int r = 0; r < 4; ++r) { pB[r] = hb ? __expf(sB[r] - m_new) : 0.f; ls += pB[r]; }
    ls += __shfl_xor(ls, 16);
    ls += __shfl_xor(ls, 32);
    l_run = l_run * alpha + ls;
    m_run = m_new;
    float aacc[4];
#pragma unroll
    for (int r = 0; r < 4; ++r) aacc[r] = __shfl(alpha, 4 * g + r);
#pragma unroll
    for (int ht = 0; ht < 16; ++ht) {
      acc[ht][0] *= aacc[0]; acc[ht][1] *= aacc[1];
      acc[ht][2] *= aacc[2]; acc[ht][3] *= aacc[3];
    }
    // redistribute P^T (D-layout) into PV A-fragment layout
    bf16x8 paf;
#pragma unroll
    for (int j = 0; j < 8; ++j) {
      const int srcl = ((2 * (g & 1) + (j >> 2)) << 4) + c;
      float va = __shfl(pA[j & 3], srcl);
      float vb = __shfl(pB[j & 3], srcl);
      float pv = (g < 2) ? va : vb;
      paf[j] = (short)f2bf(pv);
    }
    const US* vb2 = vbb + c0 + (size_t)c * 1024;
#pragma unroll
    for (int ht = 0; ht < 16; ++ht) {
      bf16x8 vf = *reinterpret_cast<const bf16x8*>(vb2 + (size_t)ht * 16384);
      acc[ht] = mfma16(paf, vf, acc[ht]);
    }
  }

  // ---- merge 4 per-wave partials ----
  if (lane < 16) {
    sml[wid][0][lane] = m_run;
    sml[wid][1][lane] = l_run;
  }
  __syncthreads();
  float beta_r[4], invL_r[4];
#pragma unroll
  for (int r = 0; r < 4; ++r) {
    const int q = 4 * g + r;
    float mw0 = sml[0][0][q], mw1 = sml[1][0][q], mw2 = sml[2][0][q], mw3 = sml[3][0][q];
    float M = fmaxf(fmaxf(mw0, mw1), fmaxf(mw2, mw3));
    float L = sml[0][1][q] * __expf(mw0 - M) + sml[1][1][q] * __expf(mw1 - M) +
              sml[2][1][q] * __expf(mw2 - M) + sml[3][1][q] * __expf(mw3 - M);
    beta_r[r] = __expf(sml[wid][0][q] - M);
    invL_r[r] = 1.0f / L;
  }
#pragma unroll
  for (int w = 0; w < 4; ++w) {
    if (wid == w) {
#pragma unroll
      for (int ht = 0; ht < 16; ++ht)
#pragma unroll
        for (int r = 0; r < 4; ++r) {
          float* p = &rbuf[(4 * g + r) * 256 + ht * 16 + c];
          float v = acc[ht][r] * beta_r[r];
          if (w == 0) *p = v; else *p += v;
        }
    }
    __syncthreads();
  }
#pragma unroll
  for (int j = 0; j < 4; ++j) {
    const int ht = 4 * wid + j;
#pragma unroll
    for (int r = 0; r < 4; ++r) {
      size_t o = ((size_t)((b * 1024 + qbase + 4 * g + r) * 8 + n)) * 256 + ht * 16 + c;
      enc[o] = f2bf(rbuf[(4 * g + r) * 256 + ht * 16 + c] * invL_r[r]);
    }
  }
}

extern "C" void kernel_launch(void* const* d_in, const int* in_sizes, int n_in,
                              void* d_out, int out_size, void* d_ws, size_t ws_size,
                              hipStream_t stream) {
  const float* x0 = (const float*)d_in[0];
  const float* x1 = (const float*)d_in[1];
  const float* wq0 = (const float*)d_in[2];
  const float* wkv0 = (const float*)d_in[3];
  const float* wo0 = (const float*)d_in[4];
  const float* wq1 = (const float*)d_in[5];
  const float* wkv1 = (const float*)d_in[6];
  const float* wo1 = (const float*)d_in[7];
  const int* pos = (const int*)d_in[8];
  float* out = (float*)d_out;

  float* out0 = out;                    // 4*768*2048
  float* out1 = out + 6291456;          // 4*256*1024
  float* k_out = out + 7340032;         // 4*1024*256
  float* v_out = out + 8388608;         // 4*1024*256

  char* ws = (char*)d_ws;
  size_t off = 0;
  auto alloc = [&](size_t bytes) {
    char* p = ws + off;
    off += (bytes + 255) & ~(size_t)255;
    return p;
  };
  US* x0b   = (US*)alloc(6291456ull * 2);
  US* x1b   = (US*)alloc(1048576ull * 2);
  US* btq0  = (US*)alloc(2048ull * 2048 * 2);
  US* btkv0 = (US*)alloc(512ull * 2048 * 2);
  US* btq1  = (US*)alloc(2048ull * 1024 * 2);
  US* btkv1 = (US*)alloc(512ull * 1024 * 2);
  US* bto0  = (US*)alloc(2048ull * 2048 * 2);
  US* bto1  = (US*)alloc(1024ull * 2048 * 2);
  float* q_raw  = (float*)alloc(8388608ull * 4);
  float* kv_raw = (float*)alloc(2097152ull * 4);
  US* q_bf = (US*)alloc(8388608ull * 2);
  US* k_bf = (US*)alloc(1048576ull * 2);
  US* vt   = (US*)alloc(1048576ull * 2 + 256);  // pad: masked-tail PV frags read past end
  US* enc  = (US*)alloc(8388608ull * 2);

  // phase 1: casts + weight packs
  k_cast<<<6144, 256, 0, stream>>>(x0, x0b, 1572864);
  k_cast<<<1024, 256, 0, stream>>>(x1, x1b, 262144);
  k_tpack<<<dim3(8, 64, 8), dim3(32, 8), 0, stream>>>(wq0, btq0, 2048, 256, 2048L * 256, 256L * 2048);
  k_tpack<<<dim3(8, 64, 2), dim3(32, 8), 0, stream>>>(wkv0, btkv0, 2048, 256, 2048L * 256, 256L * 2048);
  k_tpack<<<dim3(8, 32, 8), dim3(32, 8), 0, stream>>>(wq1, btq1, 1024, 256, 1024L * 256, 256L * 1024);
  k_tpack<<<dim3(8, 32, 2), dim3(32, 8), 0, stream>>>(wkv1, btkv1, 1024, 256, 1024L * 256, 256L * 1024);
  k_tpack<<<dim3(64, 64, 1), dim3(32, 8), 0, stream>>>(wo0, bto0, 2048, 2048, 0, 0);
  k_tpack<<<dim3(32, 64, 1), dim3(32, 8), 0, stream>>>(wo1, bto1, 2048, 1024, 0, 0);

  // phase 2: projection GEMMs (row remap fuses time-concat)
  k_gemm<0, 1><<<dim3(16, 24), 256, 0, stream>>>(x0b, btq0, q_raw, 3072, 2048, 2048);
  k_gemm<0, 1><<<dim3(4, 24), 256, 0, stream>>>(x0b, btkv0, kv_raw, 3072, 512, 2048);
  k_gemm<0, 2><<<dim3(16, 8), 256, 0, stream>>>(x1b, btq1, q_raw, 1024, 2048, 1024);
  k_gemm<0, 2><<<dim3(4, 8), 256, 0, stream>>>(x1b, btkv1, kv_raw, 1024, 512, 1024);

  // phase 3: RoPE + V transpose (also emits k, v fp32 outputs)
  k_rope<<<4096, 256, 0, stream>>>(q_raw, kv_raw, pos, q_bf, k_bf, k_out);
  k_vtrans<<<dim3(32, 8, 4), dim3(32, 8), 0, stream>>>(kv_raw, v_out, vt);

  // phase 4: causal flash attention (4-way KV split, LPT order)
  k_attn<<<dim3(64, 8, 4), 256, 0, stream>>>(q_bf, k_bf, vt, enc);

  // phase 5: output projections
  k_gemm<1, 0><<<dim3(16, 24), 256, 0, stream>>>(enc, bto0, out0, 3072, 2048, 2048);
  k_gemm<2, 0><<<dim3(8, 8), 256, 0, stream>>>(enc, bto1, out1, 1024, 1024, 2048);
}

// Round 3
// 329.296 us; speedup vs baseline: 1.5293x; 1.5293x over previous
//
#include <hip/hip_runtime.h>
#include <hip/hip_bf16.h>

typedef __attribute__((ext_vector_type(8))) short bf16x8;
typedef __attribute__((ext_vector_type(4))) float f32x4;
typedef __attribute__((ext_vector_type(4))) unsigned short u16x4;
typedef unsigned short US;

__device__ __forceinline__ f32x4 mfma16(bf16x8 a, bf16x8 b, f32x4 c) {
  return __builtin_amdgcn_mfma_f32_16x16x32_bf16(a, b, c, 0, 0, 0);
}

__device__ __forceinline__ US f2bf(float f) {
  union { float f; unsigned u; } x; x.f = f;
  unsigned r = x.u + 0x7fffu + ((x.u >> 16) & 1u);
  return (US)(r >> 16);
}

// async global->LDS, 16B per lane; LDS dest = wave-uniform base + lane*16
__device__ __forceinline__ void gld16(const US* gp, US* lp) {
  __builtin_amdgcn_global_load_lds(
      (const __attribute__((address_space(1))) unsigned*)gp,
      (__attribute__((address_space(3))) unsigned*)lp, 16, 0, 0);
}

// row remap fusing the time-concat: mode1: r=b*768+s -> b*1024+s ; mode2: r=b*256+s -> b*1024+768+s
__device__ __forceinline__ int map_row(int r, int mode) {
  if (mode == 1) { int b = r / 768; return b * 1024 + (r - b * 768); }
  if (mode == 2) { int b = r >> 8; return b * 1024 + 768 + (r & 255); }
  return r;
}

// ----------------- fp32 -> bf16 cast -----------------
__global__ void k_cast(const float* __restrict__ src, US* __restrict__ dst, int n4) {
  int i = blockIdx.x * 256 + threadIdx.x;
  if (i >= n4) return;
  f32x4 v = *reinterpret_cast<const f32x4*>(src + (size_t)i * 4);
  u16x4 o;
  o[0] = f2bf(v[0]); o[1] = f2bf(v[1]); o[2] = f2bf(v[2]); o[3] = f2bf(v[3]);
  *reinterpret_cast<u16x4*>(dst + (size_t)i * 4) = o;
}

// ------- batched transpose-pack: fp32 src[R][C] -> bf16 dst[C][R] -------
__global__ __launch_bounds__(256)
void k_tpack(const float* __restrict__ src, US* __restrict__ dst,
             int R, int C, long sbs, long dbs) {
  __shared__ float tile[32][33];
  int c0 = blockIdx.x * 32, r0 = blockIdx.y * 32;
  src += (long)blockIdx.z * sbs;
  dst += (long)blockIdx.z * dbs;
  int tx = threadIdx.x, ty = threadIdx.y;
#pragma unroll
  for (int i = 0; i < 4; ++i)
    tile[ty + 8 * i][tx] = src[(size_t)(r0 + ty + 8 * i) * C + c0 + tx];
  __syncthreads();
#pragma unroll
  for (int i = 0; i < 4; ++i)
    dst[(size_t)(c0 + ty + 8 * i) * R + r0 + tx] = f2bf(tile[tx][ty + 8 * i]);
}

// ------- bf16 GEMM: C[M,N] = A[M,K] * BT[N,K]^T, fp32 out, 128x128x32 tile -------
// m97 structure: global_load_lds width=16 staging, linear LDS, 2 barriers/K-step
template <int AMAP, int CMAP>
__global__ __launch_bounds__(256, 2)
void k_gemm(const US* __restrict__ A, const US* __restrict__ BT, float* __restrict__ C,
            int M, int N, int K) {
  __shared__ __align__(16) US lA[128 * 32];
  __shared__ __align__(16) US lB[128 * 32];
  const int tid = threadIdx.x;
  const int lane = tid & 63;
  const int wid = tid >> 6;
  const int wm = wid >> 1, wn = wid & 1;
  const int m0 = blockIdx.y * 128, n0 = blockIdx.x * 128;
  const int g = lane >> 4, c = lane & 15;

  // staging addresses: lane covers row (base + lane/4), 16B at col (lane&3)*8
  const int lrow = lane >> 2;
  const int lcol = (lane & 3) * 8;
  const size_t ga0 = (size_t)map_row(m0 + wid * 16 + lrow, AMAP) * K + lcol;
  const size_t ga1 = (size_t)map_row(m0 + 64 + wid * 16 + lrow, AMAP) * K + lcol;
  const size_t gb0 = (size_t)(n0 + wid * 16 + lrow) * K + lcol;
  const size_t gb1 = (size_t)(n0 + 64 + wid * 16 + lrow) * K + lcol;
  US* ldA0 = &lA[(wid * 16) * 32];
  US* ldA1 = &lA[(64 + wid * 16) * 32];
  US* ldB0 = &lB[(wid * 16) * 32];
  US* ldB1 = &lB[(64 + wid * 16) * 32];

  f32x4 acc[4][4];
#pragma unroll
  for (int i = 0; i < 4; ++i)
#pragma unroll
    for (int j = 0; j < 4; ++j) acc[i][j] = f32x4{0.f, 0.f, 0.f, 0.f};

  for (int k0 = 0; k0 < K; k0 += 32) {
    __syncthreads();  // previous iter's reads done before overwrite
    gld16(A + ga0 + k0, ldA0);
    gld16(A + ga1 + k0, ldA1);
    gld16(BT + gb0 + k0, ldB0);
    gld16(BT + gb1 + k0, ldB1);
    __syncthreads();  // compiler drains vmcnt(0) before barrier -> LDS ready
    bf16x8 af[4], bfr[4];
#pragma unroll
    for (int i = 0; i < 4; ++i) {
      af[i] = *reinterpret_cast<const bf16x8*>(&lA[(wm * 64 + i * 16 + c) * 32 + g * 8]);
      bfr[i] = *reinterpret_cast<const bf16x8*>(&lB[(wn * 64 + i * 16 + c) * 32 + g * 8]);
    }
#pragma unroll
    for (int i = 0; i < 4; ++i)
#pragma unroll
      for (int j = 0; j < 4; ++j)
        acc[i][j] = mfma16(af[i], bfr[j], acc[i][j]);
  }
#pragma unroll
  for (int i = 0; i < 4; ++i) {
#pragma unroll
    for (int r = 0; r < 4; ++r) {
      int orow = map_row(m0 + wm * 64 + i * 16 + 4 * g + r, CMAP);
      float* cp = C + (size_t)orow * N + n0 + wn * 64 + c;
#pragma unroll
      for (int j = 0; j < 4; ++j) cp[j * 16] = acc[i][j][r];
    }
  }
}

// ------- RoPE: q_raw(f32)->q_bf (roped*scale), kv_raw k-part -> k_bf + k_out(f32) -------
__global__ __launch_bounds__(256)
void k_rope(const float* __restrict__ q_raw, const float* __restrict__ kv_raw,
            const int* __restrict__ pos, US* __restrict__ q_bf,
            US* __restrict__ k_bf, float* __restrict__ k_out) {
  __shared__ float sa[128], ca[128];
  const int bt = blockIdx.x;
  const int tid = threadIdx.x;
  const int p = pos[bt];
  if (tid < 128) {
    float inv_ts = powf(10000.0f, -(float)tid * (1.0f / 128.0f));
    float r = (float)p * inv_ts;
    sa[tid] = sinf(r);
    ca[tid] = cosf(r);
  }
  __syncthreads();
  const float scale = 0.0625f;  // 256^-0.5
  const size_t qo = (size_t)bt * 2048;
#pragma unroll
  for (int it = 0; it < 4; ++it) {
    int idx = it * 256 + tid;
    int n = idx >> 7, j = idx & 127;
    float x1 = q_raw[qo + n * 256 + j];
    float x2 = q_raw[qo + n * 256 + j + 128];
    float s = sa[j], co = ca[j];
    q_bf[qo + n * 256 + j] = f2bf(scale * (x1 * co - x2 * s));
    q_bf[qo + n * 256 + j + 128] = f2bf(scale * (x2 * co + x1 * s));
  }
  if (tid < 128) {
    int j = tid;
    const size_t ko = (size_t)bt * 512;
    float x1 = kv_raw[ko + j], x2 = kv_raw[ko + j + 128];
    float s = sa[j], co = ca[j];
    float o1 = x1 * co - x2 * s, o2 = x2 * co + x1 * s;
    const size_t kd = (size_t)bt * 256;
    k_bf[kd + j] = f2bf(o1);
    k_bf[kd + j + 128] = f2bf(o2);
    k_out[kd + j] = o1;
    k_out[kd + j + 128] = o2;
  }
}

// ------- V: kv_raw v-part -> v_out(f32) + vt bf16 [b][h][t] -------
__global__ __launch_bounds__(256)
void k_vtrans(const float* __restrict__ kv_raw, float* __restrict__ v_out, US* __restrict__ vt) {
  __shared__ float tile[32][33];
  int t0 = blockIdx.x * 32, h0 = blockIdx.y * 32, b = blockIdx.z;
  int tx = threadIdx.x, ty = threadIdx.y;
#pragma unroll
  for (int i = 0; i < 4; ++i) {
    int t = t0 + ty + 8 * i;
    float v = kv_raw[(size_t)(b * 1024 + t) * 512 + 256 + h0 + tx];
    tile[ty + 8 * i][tx] = v;
    v_out[(size_t)(b * 1024 + t) * 256 + h0 + tx] = v;
  }
  __syncthreads();
#pragma unroll
  for (int i = 0; i < 4; ++i) {
    int h = h0 + ty + 8 * i;
    vt[(size_t)(b * 256 + h) * 1024 + t0 + tx] = f2bf(tile[tx][ty + 8 * i]);
  }
}

// ------- flash attention: block = (qt, b); 8 waves = 8 heads sharing K/V via LDS -------
// K chunk [32 kvcol][256 h] and V^T chunk [256 h][32 kvcol] staged with global_load_lds,
// double-buffered (stage i+1 during compute of i, 1 barrier/chunk). Both tiles XOR-swizzled
// (both-sides: pre-swizzled global source + swizzled ds_read; linear LDS dest).
__global__ __launch_bounds__(512, 2)
void k_attn(const US* __restrict__ qb, const US* __restrict__ kb,
            const US* __restrict__ vt, US* __restrict__ enc) {
  __shared__ __align__(16) US lK[2][32 * 256];   // 16KB x2
  __shared__ __align__(16) US lV[2][256 * 32];   // 16KB x2
  const int qt = blockIdx.x, b = blockIdx.y;
  const int tid = threadIdx.x;
  const int wid = tid >> 6;   // head index
  const int lane = tid & 63;
  const int g = lane >> 4, c = lane & 15;
  const int qbase = qt * 16;
  const int n = wid;

  const US* kbB = kb + (size_t)b * 262144;
  const US* vtB = vt + (size_t)b * 262144;

  // per-head Q fragments
  bf16x8 qf[8];
  {
    const US* qp = qb + ((size_t)((b * 1024 + qbase + c) * 8 + n)) * 256 + 8 * g;
#pragma unroll
    for (int ch = 0; ch < 8; ++ch)
      qf[ch] = *reinterpret_cast<const bf16x8*>(qp + ch * 32);
  }

  // stage chunk [c0..c0+31] into buffer bi.
  // K granule (r,s) in LDS holds global K col-granule s^(r&7) of kv-row c0+r.
  // V granule (r,s) holds global V^T col-granule s^((r>>1)&3) of h-row r.
  auto stage = [&](int bi, int c0) {
#pragma unroll
    for (int j = 0; j < 2; ++j) {
      const int rk = wid * 4 + j * 2 + (lane >> 5);
      const int sk = lane & 31;
      gld16(kbB + (size_t)(c0 + rk) * 256 + (sk ^ (rk & 7)) * 8,
            &lK[bi][(wid * 4 + j * 2) * 256]);
      const int rv = wid * 32 + j * 16 + (lane >> 2);
      const int sv = lane & 3;
      gld16(vtB + (size_t)rv * 1024 + c0 + (sv ^ ((rv >> 1) & 3)) * 8,
            &lV[bi][(wid * 32 + j * 16) * 32]);
    }
  };

  f32x4 acc[16];
#pragma unroll
  for (int i = 0; i < 16; ++i) acc[i] = f32x4{0.f, 0.f, 0.f, 0.f};
  float m_run = -3.0e38f, l_run = 0.f;

  const int nC = qbase / 32 + 1;
  stage(0, 0);
  __syncthreads();

  for (int i = 0; i < nC; ++i) {
    const int c0 = 32 * i;
    const int bi = i & 1;
    if (i + 1 < nC) stage((i + 1) & 1, c0 + 32);

    const bool hb = (c0 + 16 <= qbase);
    f32x4 sA = {0.f, 0.f, 0.f, 0.f}, sB = {0.f, 0.f, 0.f, 0.f};
#pragma unroll
    for (int ch = 0; ch < 8; ++ch) {
      const int slot = (((ch * 4 + g) ^ (c & 7)) * 8);
      sA = mfma16(*reinterpret_cast<const bf16x8*>(&lK[bi][c * 256 + slot]), qf[ch], sA);
    }
    if (hb) {
#pragma unroll
      for (int ch = 0; ch < 8; ++ch) {
        const int slot = (((ch * 4 + g) ^ (c & 7)) * 8);  // (c+16)&7 == c&7
        sB = mfma16(*reinterpret_cast<const bf16x8*>(&lK[bi][(c + 16) * 256 + slot]), qf[ch], sB);
      }
    }
    // causal mask on diagonal tiles: kv-row (4g+r) > q-row c
    if (c0 == qbase) {
#pragma unroll
      for (int r = 0; r < 4; ++r)
        if (4 * g + r > c) sA[r] = -3.0e38f;
    }
    if (hb && (c0 + 16 == qbase)) {
#pragma unroll
      for (int r = 0; r < 4; ++r)
        if (4 * g + r > c) sB[r] = -3.0e38f;
    }
    // per-q-row (column c) online softmax
    float tm = fmaxf(fmaxf(sA[0], sA[1]), fmaxf(sA[2], sA[3]));
    if (hb) tm = fmaxf(tm, fmaxf(fmaxf(sB[0], sB[1]), fmaxf(sB[2], sB[3])));
    tm = fmaxf(tm, __shfl_xor(tm, 16));
    tm = fmaxf(tm, __shfl_xor(tm, 32));
    const float m_new = fmaxf(m_run, tm);
    const float alpha = __expf(m_run - m_new);
    float pA[4], pB[4];
    float ls = 0.f;
#pragma unroll
    for (int r = 0; r < 4; ++r) { pA[r] = __expf(sA[r] - m_new); ls += pA[r]; }
#pragma unroll
    for (int r = 0; r < 4; ++r) { pB[r] = hb ? __expf(sB[r] - m_new) : 0.f; ls += pB[r]; }
    ls += __shfl_xor(ls, 16);
    ls += __shfl_xor(ls, 32);
    l_run = l_run * alpha + ls;
    m_run = m_new;
    float aacc[4];
#pragma unroll
    for (int r = 0; r < 4; ++r) aacc[r] = __shfl(alpha, 4 * g + r);
#pragma unroll
    for (int ht = 0; ht < 16; ++ht) {
      acc[ht][0] *= aacc[0]; acc[ht][1] *= aacc[1];
      acc[ht][2] *= aacc[2]; acc[ht][3] *= aacc[3];
    }
    // redistribute P^T (D-layout) into PV A-fragment layout
    bf16x8 paf;
#pragma unroll
    for (int j = 0; j < 8; ++j) {
      const int srcl = ((2 * (g & 1) + (j >> 2)) << 4) + c;
      float va = __shfl(pA[j & 3], srcl);
      float vb = __shfl(pB[j & 3], srcl);
      float pv = (g < 2) ? va : vb;
      paf[j] = (short)f2bf(pv);
    }
#pragma unroll
    for (int ht = 0; ht < 16; ++ht) {
      const int h = ht * 16 + c;
      const int slot = (g ^ ((c >> 1) & 3)) * 8;
      bf16x8 vf = *reinterpret_cast<const bf16x8*>(&lV[bi][h * 32 + slot]);
      acc[ht] = mfma16(paf, vf, acc[ht]);
    }
    __syncthreads();  // buf[bi] reads done by all waves; staging of buf[bi^1] drained
  }

  const float inv = 1.0f / l_run;
  float ia[4];
#pragma unroll
  for (int r = 0; r < 4; ++r) ia[r] = __shfl(inv, 4 * g + r);
#pragma unroll
  for (int ht = 0; ht < 16; ++ht) {
#pragma unroll
    for (int r = 0; r < 4; ++r) {
      size_t o = ((size_t)((b * 1024 + qbase + 4 * g + r) * 8 + n)) * 256 + ht * 16 + c;
      enc[o] = f2bf(acc[ht][r] * ia[r]);
    }
  }
}

extern "C" void kernel_launch(void* const* d_in, const int* in_sizes, int n_in,
                              void* d_out, int out_size, void* d_ws, size_t ws_size,
                              hipStream_t stream) {
  const float* x0 = (const float*)d_in[0];
  const float* x1 = (const float*)d_in[1];
  const float* wq0 = (const float*)d_in[2];
  const float* wkv0 = (const float*)d_in[3];
  const float* wo0 = (const float*)d_in[4];
  const float* wq1 = (const float*)d_in[5];
  const float* wkv1 = (const float*)d_in[6];
  const float* wo1 = (const float*)d_in[7];
  const int* pos = (const int*)d_in[8];
  float* out = (float*)d_out;

  float* out0 = out;                    // 4*768*2048
  float* out1 = out + 6291456;          // 4*256*1024
  float* k_out = out + 7340032;         // 4*1024*256
  float* v_out = out + 8388608;         // 4*1024*256

  char* ws = (char*)d_ws;
  size_t off = 0;
  auto alloc = [&](size_t bytes) {
    char* p = ws + off;
    off += (bytes + 255) & ~(size_t)255;
    return p;
  };
  US* x0b   = (US*)alloc(6291456ull * 2);
  US* x1b   = (US*)alloc(1048576ull * 2);
  US* btq0  = (US*)alloc(2048ull * 2048 * 2);
  US* btkv0 = (US*)alloc(512ull * 2048 * 2);
  US* btq1  = (US*)alloc(2048ull * 1024 * 2);
  US* btkv1 = (US*)alloc(512ull * 1024 * 2);
  US* bto0  = (US*)alloc(2048ull * 2048 * 2);
  US* bto1  = (US*)alloc(1024ull * 2048 * 2);
  float* q_raw  = (float*)alloc(8388608ull * 4);
  float* kv_raw = (float*)alloc(2097152ull * 4);
  US* q_bf = (US*)alloc(8388608ull * 2);
  US* k_bf = (US*)alloc(1048576ull * 2);
  US* vt   = (US*)alloc(1048576ull * 2 + 256);
  US* enc  = (US*)alloc(8388608ull * 2);

  // phase 1: casts + weight packs
  k_cast<<<6144, 256, 0, stream>>>(x0, x0b, 1572864);
  k_cast<<<1024, 256, 0, stream>>>(x1, x1b, 262144);
  k_tpack<<<dim3(8, 64, 8), dim3(32, 8), 0, stream>>>(wq0, btq0, 2048, 256, 2048L * 256, 256L * 2048);
  k_tpack<<<dim3(8, 64, 2), dim3(32, 8), 0, stream>>>(wkv0, btkv0, 2048, 256, 2048L * 256, 256L * 2048);
  k_tpack<<<dim3(8, 32, 8), dim3(32, 8), 0, stream>>>(wq1, btq1, 1024, 256, 1024L * 256, 256L * 1024);
  k_tpack<<<dim3(8, 32, 2), dim3(32, 8), 0, stream>>>(wkv1, btkv1, 1024, 256, 1024L * 256, 256L * 1024);
  k_tpack<<<dim3(64, 64, 1), dim3(32, 8), 0, stream>>>(wo0, bto0, 2048, 2048, 0, 0);
  k_tpack<<<dim3(32, 64, 1), dim3(32, 8), 0, stream>>>(wo1, bto1, 2048, 1024, 0, 0);

  // phase 2: projection GEMMs (row remap fuses time-concat)
  k_gemm<0, 1><<<dim3(16, 24), 256, 0, stream>>>(x0b, btq0, q_raw, 3072, 2048, 2048);
  k_gemm<0, 1><<<dim3(4, 24), 256, 0, stream>>>(x0b, btkv0, kv_raw, 3072, 512, 2048);
  k_gemm<0, 2><<<dim3(16, 8), 256, 0, stream>>>(x1b, btq1, q_raw, 1024, 2048, 1024);
  k_gemm<0, 2><<<dim3(4, 8), 256, 0, stream>>>(x1b, btkv1, kv_raw, 1024, 512, 1024);

  // phase 3: RoPE + V transpose (also emits k, v fp32 outputs)
  k_rope<<<4096, 256, 0, stream>>>(q_raw, kv_raw, pos, q_bf, k_bf, k_out);
  k_vtrans<<<dim3(32, 8, 4), dim3(32, 8), 0, stream>>>(kv_raw, v_out, vt);

  // phase 4: causal flash attention (8 heads share LDS-staged K/V per block)
  k_attn<<<dim3(64, 4), 512, 0, stream>>>(q_bf, k_bf, vt, enc);

  // phase 5: output projections
  k_gemm<1, 0><<<dim3(16, 24), 256, 0, stream>>>(enc, bto0, out0, 3072, 2048, 2048);
  k_gemm<2, 0><<<dim3(8, 8), 256, 0, stream>>>(enc, bto1, out1, 1024, 1024, 2048);
}

// Round 4
// 226.022 us; speedup vs baseline: 2.2280x; 1.4569x over previous
//
#include <hip/hip_runtime.h>
#include <hip/hip_bf16.h>

typedef __attribute__((ext_vector_type(8))) short bf16x8;
typedef __attribute__((ext_vector_type(4))) float f32x4;
typedef __attribute__((ext_vector_type(4))) unsigned short u16x4;
typedef unsigned short US;

__device__ __forceinline__ f32x4 mfma16(bf16x8 a, bf16x8 b, f32x4 c) {
  return __builtin_amdgcn_mfma_f32_16x16x32_bf16(a, b, c, 0, 0, 0);
}

__device__ __forceinline__ US f2bf(float f) {
  union { float f; unsigned u; } x; x.f = f;
  unsigned r = x.u + 0x7fffu + ((x.u >> 16) & 1u);
  return (US)(r >> 16);
}

// async global->LDS, 16B per lane; LDS dest = wave-uniform base + lane*16
__device__ __forceinline__ void gld16(const US* gp, US* lp) {
  __builtin_amdgcn_global_load_lds(
      (const __attribute__((address_space(1))) unsigned*)gp,
      (__attribute__((address_space(3))) unsigned*)lp, 16, 0, 0);
}

// row remap fusing the time-concat: mode1: r=b*768+s -> b*1024+s ; mode2: r=b*256+s -> b*1024+768+s
__device__ __forceinline__ int map_row(int r, int mode) {
  if (mode == 1) { int b = r / 768; return b * 1024 + (r - b * 768); }
  if (mode == 2) { int b = r >> 8; return b * 1024 + 768 + (r & 255); }
  return r;
}

// ----------------- fp32 -> bf16 cast -----------------
__global__ void k_cast(const float* __restrict__ src, US* __restrict__ dst, int n4) {
  int i = blockIdx.x * 256 + threadIdx.x;
  if (i >= n4) return;
  f32x4 v = *reinterpret_cast<const f32x4*>(src + (size_t)i * 4);
  u16x4 o;
  o[0] = f2bf(v[0]); o[1] = f2bf(v[1]); o[2] = f2bf(v[2]); o[3] = f2bf(v[3]);
  *reinterpret_cast<u16x4*>(dst + (size_t)i * 4) = o;
}

// ------- batched transpose-pack: fp32 src[R][C] -> bf16 dst[C][R] -------
__global__ __launch_bounds__(256)
void k_tpack(const float* __restrict__ src, US* __restrict__ dst,
             int R, int C, long sbs, long dbs) {
  __shared__ float tile[32][33];
  int c0 = blockIdx.x * 32, r0 = blockIdx.y * 32;
  src += (long)blockIdx.z * sbs;
  dst += (long)blockIdx.z * dbs;
  int tx = threadIdx.x, ty = threadIdx.y;
#pragma unroll
  for (int i = 0; i < 4; ++i)
    tile[ty + 8 * i][tx] = src[(size_t)(r0 + ty + 8 * i) * C + c0 + tx];
  __syncthreads();
#pragma unroll
  for (int i = 0; i < 4; ++i)
    dst[(size_t)(c0 + ty + 8 * i) * R + r0 + tx] = f2bf(tile[tx][ty + 8 * i]);
}

// ------- fused QKV projection GEMM: A[M,K] x BT[2560,K]^T -> q_raw / kv_raw -------
// double-buffered LDS with prefetch-before-compute (1 barrier/K-step)
template <int CMAP>
__global__ __launch_bounds__(256, 2)
void k_gemm_qkv(const US* __restrict__ A, const US* __restrict__ BT,
                float* __restrict__ Cq, float* __restrict__ Ckv,
                int M, int K) {
  __shared__ __align__(16) US lA[2][128 * 32];
  __shared__ __align__(16) US lB[2][128 * 32];
  const int tid = threadIdx.x;
  const int lane = tid & 63;
  const int wid = tid >> 6;
  const int wm = wid >> 1, wn = wid & 1;
  const int m0 = blockIdx.y * 128, n0 = blockIdx.x * 128;
  const int g = lane >> 4, c = lane & 15;
  const int lrow = lane >> 2, lcol = (lane & 3) * 8;
  const size_t ga0 = (size_t)(m0 + wid * 16 + lrow) * K + lcol;
  const size_t ga1 = (size_t)(m0 + 64 + wid * 16 + lrow) * K + lcol;
  const size_t gb0 = (size_t)(n0 + wid * 16 + lrow) * K + lcol;
  const size_t gb1 = (size_t)(n0 + 64 + wid * 16 + lrow) * K + lcol;

  auto stage = [&](int bi, int k0) {
    gld16(A + ga0 + k0, &lA[bi][(wid * 16) * 32]);
    gld16(A + ga1 + k0, &lA[bi][(64 + wid * 16) * 32]);
    gld16(BT + gb0 + k0, &lB[bi][(wid * 16) * 32]);
    gld16(BT + gb1 + k0, &lB[bi][(64 + wid * 16) * 32]);
  };

  f32x4 acc[4][4];
#pragma unroll
  for (int i = 0; i < 4; ++i)
#pragma unroll
    for (int j = 0; j < 4; ++j) acc[i][j] = f32x4{0.f, 0.f, 0.f, 0.f};

  const int nt = K >> 5;
  stage(0, 0);
  __syncthreads();
  for (int t = 0; t < nt; ++t) {
    const int bi = t & 1;
    if (t + 1 < nt) stage(bi ^ 1, (t + 1) * 32);
    bf16x8 af[4], bfr[4];
#pragma unroll
    for (int i = 0; i < 4; ++i) {
      af[i] = *reinterpret_cast<const bf16x8*>(&lA[bi][(wm * 64 + i * 16 + c) * 32 + g * 8]);
      bfr[i] = *reinterpret_cast<const bf16x8*>(&lB[bi][(wn * 64 + i * 16 + c) * 32 + g * 8]);
    }
#pragma unroll
    for (int i = 0; i < 4; ++i)
#pragma unroll
      for (int j = 0; j < 4; ++j)
        acc[i][j] = mfma16(af[i], bfr[j], acc[i][j]);
    __syncthreads();  // drains vmcnt(0): prefetch landed; buf[bi] reads done
  }

  const bool isq = (n0 < 2048);
  float* Cb = isq ? Cq : Ckv;
  const int Nst = isq ? 2048 : 512;
  const int nb = (isq ? n0 : n0 - 2048) + wn * 64 + c;
#pragma unroll
  for (int i = 0; i < 4; ++i) {
#pragma unroll
    for (int r = 0; r < 4; ++r) {
      int orow = map_row(m0 + wm * 64 + i * 16 + 4 * g + r, CMAP);
      float* cp = Cb + (size_t)orow * Nst + nb;
#pragma unroll
      for (int j = 0; j < 4; ++j) cp[j * 16] = acc[i][j][r];
    }
  }
}

// ------- fused output GEMM: enc[4096,2048] -> out0 (rows s<768) / out1 (rows s>=768) -------
__global__ __launch_bounds__(256, 2)
void k_gemm_out(const US* __restrict__ A, const US* __restrict__ BT0, const US* __restrict__ BT1,
                float* __restrict__ C0, float* __restrict__ C1) {
  const int m0 = blockIdx.y * 128, n0 = blockIdx.x * 128;
  const int s0 = m0 & 1023;
  const bool is0 = (s0 < 768);
  if (!is0 && n0 >= 1024) return;
  const US* __restrict__ BT = is0 ? BT0 : BT1;
  const int K = 2048;
  __shared__ __align__(16) US lA[2][128 * 32];
  __shared__ __align__(16) US lB[2][128 * 32];
  const int tid = threadIdx.x;
  const int lane = tid & 63;
  const int wid = tid >> 6;
  const int wm = wid >> 1, wn = wid & 1;
  const int g = lane >> 4, c = lane & 15;
  const int lrow = lane >> 2, lcol = (lane & 3) * 8;
  const size_t ga0 = (size_t)(m0 + wid * 16 + lrow) * K + lcol;
  const size_t ga1 = (size_t)(m0 + 64 + wid * 16 + lrow) * K + lcol;
  const size_t gb0 = (size_t)(n0 + wid * 16 + lrow) * K + lcol;
  const size_t gb1 = (size_t)(n0 + 64 + wid * 16 + lrow) * K + lcol;

  auto stage = [&](int bi, int k0) {
    gld16(A + ga0 + k0, &lA[bi][(wid * 16) * 32]);
    gld16(A + ga1 + k0, &lA[bi][(64 + wid * 16) * 32]);
    gld16(BT + gb0 + k0, &lB[bi][(wid * 16) * 32]);
    gld16(BT + gb1 + k0, &lB[bi][(64 + wid * 16) * 32]);
  };

  f32x4 acc[4][4];
#pragma unroll
  for (int i = 0; i < 4; ++i)
#pragma unroll
    for (int j = 0; j < 4; ++j) acc[i][j] = f32x4{0.f, 0.f, 0.f, 0.f};

  const int nt = K >> 5;
  stage(0, 0);
  __syncthreads();
  for (int t = 0; t < nt; ++t) {
    const int bi = t & 1;
    if (t + 1 < nt) stage(bi ^ 1, (t + 1) * 32);
    bf16x8 af[4], bfr[4];
#pragma unroll
    for (int i = 0; i < 4; ++i) {
      af[i] = *reinterpret_cast<const bf16x8*>(&lA[bi][(wm * 64 + i * 16 + c) * 32 + g * 8]);
      bfr[i] = *reinterpret_cast<const bf16x8*>(&lB[bi][(wn * 64 + i * 16 + c) * 32 + g * 8]);
    }
#pragma unroll
    for (int i = 0; i < 4; ++i)
#pragma unroll
      for (int j = 0; j < 4; ++j)
        acc[i][j] = mfma16(af[i], bfr[j], acc[i][j]);
    __syncthreads();
  }

  const int col = n0 + wn * 64 + c;
#pragma unroll
  for (int i = 0; i < 4; ++i) {
#pragma unroll
    for (int r = 0; r < 4; ++r) {
      const int rf = m0 + wm * 64 + i * 16 + 4 * g + r;
      const int b = rf >> 10, s = rf & 1023;
      float* cp = is0 ? (C0 + (size_t)(b * 768 + s) * 2048 + col)
                      : (C1 + (size_t)(b * 256 + s - 768) * 1024 + col);
#pragma unroll
      for (int j = 0; j < 4; ++j) cp[j * 16] = acc[i][j][r];
    }
  }
}

// ------- RoPE: q_raw(f32)->q_bf (roped*scale), kv_raw k-part -> k_bf + k_out(f32) -------
__global__ __launch_bounds__(256)
void k_rope(const float* __restrict__ q_raw, const float* __restrict__ kv_raw,
            const int* __restrict__ pos, US* __restrict__ q_bf,
            US* __restrict__ k_bf, float* __restrict__ k_out) {
  __shared__ float sa[128], ca[128];
  const int bt = blockIdx.x;
  const int tid = threadIdx.x;
  const int p = pos[bt];
  if (tid < 128) {
    float inv_ts = powf(10000.0f, -(float)tid * (1.0f / 128.0f));
    float r = (float)p * inv_ts;
    sa[tid] = sinf(r);
    ca[tid] = cosf(r);
  }
  __syncthreads();
  const float scale = 0.0625f;  // 256^-0.5
  const size_t qo = (size_t)bt * 2048;
#pragma unroll
  for (int it = 0; it < 4; ++it) {
    int idx = it * 256 + tid;
    int n = idx >> 7, j = idx & 127;
    float x1 = q_raw[qo + n * 256 + j];
    float x2 = q_raw[qo + n * 256 + j + 128];
    float s = sa[j], co = ca[j];
    q_bf[qo + n * 256 + j] = f2bf(scale * (x1 * co - x2 * s));
    q_bf[qo + n * 256 + j + 128] = f2bf(scale * (x2 * co + x1 * s));
  }
  if (tid < 128) {
    int j = tid;
    const size_t ko = (size_t)bt * 512;
    float x1 = kv_raw[ko + j], x2 = kv_raw[ko + j + 128];
    float s = sa[j], co = ca[j];
    float o1 = x1 * co - x2 * s, o2 = x2 * co + x1 * s;
    const size_t kd = (size_t)bt * 256;
    k_bf[kd + j] = f2bf(o1);
    k_bf[kd + j + 128] = f2bf(o2);
    k_out[kd + j] = o1;
    k_out[kd + j + 128] = o2;
  }
}

// ------- V: kv_raw v-part -> v_out(f32) + vt bf16 [b][h][t] -------
__global__ __launch_bounds__(256)
void k_vtrans(const float* __restrict__ kv_raw, float* __restrict__ v_out, US* __restrict__ vt) {
  __shared__ float tile[32][33];
  int t0 = blockIdx.x * 32, h0 = blockIdx.y * 32, b = blockIdx.z;
  int tx = threadIdx.x, ty = threadIdx.y;
#pragma unroll
  for (int i = 0; i < 4; ++i) {
    int t = t0 + ty + 8 * i;
    float v = kv_raw[(size_t)(b * 1024 + t) * 512 + 256 + h0 + tx];
    tile[ty + 8 * i][tx] = v;
    v_out[(size_t)(b * 1024 + t) * 256 + h0 + tx] = v;
  }
  __syncthreads();
#pragma unroll
  for (int i = 0; i < 4; ++i) {
    int h = h0 + ty + 8 * i;
    vt[(size_t)(b * 256 + h) * 1024 + t0 + tx] = f2bf(tile[tx][ty + 8 * i]);
  }
}

// ------- flash attention: 512 blocks (qt x head-half x b), 4 waves = 4 heads -------
// K/V chunk staged to LDS (double-buffered, XOR-swizzled both-sides). Work-ranked
// blockIdx pairing: blocks c and c+256 (same CU under round-robin) get ranks r and
// 511-r -> per-CU work uniform. Defer-max (THR=8) skips acc rescale when max stable.
__global__ __launch_bounds__(256, 2)
void k_attn(const US* __restrict__ qb, const US* __restrict__ kb,
            const US* __restrict__ vt, US* __restrict__ enc) {
  __shared__ __align__(16) US lK[2][32 * 256];   // 16KB x2
  __shared__ __align__(16) US lV[2][256 * 32];   // 16KB x2
  const int id = blockIdx.x;
  const int r0_ = (id < 256) ? id : 767 - id;    // work rank, descending length
  const int qt = 63 - (r0_ >> 3);
  const int hg = (r0_ >> 2) & 1;
  const int b = r0_ & 3;
  const int tid = threadIdx.x;
  const int wid = tid >> 6;
  const int lane = tid & 63;
  const int g = lane >> 4, c = lane & 15;
  const int qbase = qt * 16;
  const int n = hg * 4 + wid;

  const US* kbB = kb + (size_t)b * 262144;
  const US* vtB = vt + (size_t)b * 262144;

  bf16x8 qf[8];
  {
    const US* qp = qb + ((size_t)((b * 1024 + qbase + c) * 8 + n)) * 256 + 8 * g;
#pragma unroll
    for (int ch = 0; ch < 8; ++ch)
      qf[ch] = *reinterpret_cast<const bf16x8*>(qp + ch * 32);
  }

  // stage chunk [c0..c0+31]: K granule (r,s) holds global col-granule s^(r&7);
  // V granule (r,s) holds global col-granule s^((r>>1)&3). 4 waves cover the tiles.
  auto stage = [&](int bi, int c0) {
#pragma unroll
    for (int j = 0; j < 4; ++j) {
      const int rk = wid * 8 + j * 2 + (lane >> 5);
      const int sk = lane & 31;
      gld16(kbB + (size_t)(c0 + rk) * 256 + (sk ^ (rk & 7)) * 8,
            &lK[bi][(wid * 8 + j * 2) * 256]);
      const int rv = wid * 64 + j * 16 + (lane >> 2);
      const int sv = lane & 3;
      gld16(vtB + (size_t)rv * 1024 + c0 + (sv ^ ((rv >> 1) & 3)) * 8,
            &lV[bi][(wid * 64 + j * 16) * 32]);
    }
  };

  f32x4 acc[16];
#pragma unroll
  for (int i = 0; i < 16; ++i) acc[i] = f32x4{0.f, 0.f, 0.f, 0.f};
  float m_run = -3.0e38f, l_run = 0.f;

  const int nC = qbase / 32 + 1;
  stage(0, 0);
  __syncthreads();

  for (int i = 0; i < nC; ++i) {
    const int c0 = 32 * i;
    const int bi = i & 1;
    if (i + 1 < nC) stage(bi ^ 1, c0 + 32);

    const bool hb = (c0 + 16 <= qbase);
    f32x4 sA = {0.f, 0.f, 0.f, 0.f}, sB = {0.f, 0.f, 0.f, 0.f};
#pragma unroll
    for (int ch = 0; ch < 8; ++ch) {
      const int slot = (((ch * 4 + g) ^ (c & 7)) * 8);
      sA = mfma16(*reinterpret_cast<const bf16x8*>(&lK[bi][c * 256 + slot]), qf[ch], sA);
    }
    if (hb) {
#pragma unroll
      for (int ch = 0; ch < 8; ++ch) {
        const int slot = (((ch * 4 + g) ^ (c & 7)) * 8);  // (c+16)&7 == c&7
        sB = mfma16(*reinterpret_cast<const bf16x8*>(&lK[bi][(c + 16) * 256 + slot]), qf[ch], sB);
      }
    }
    if (c0 == qbase) {
#pragma unroll
      for (int r = 0; r < 4; ++r)
        if (4 * g + r > c) sA[r] = -3.0e38f;
    }
    if (hb && (c0 + 16 == qbase)) {
#pragma unroll
      for (int r = 0; r < 4; ++r)
        if (4 * g + r > c) sB[r] = -3.0e38f;
    }
    float tm = fmaxf(fmaxf(sA[0], sA[1]), fmaxf(sA[2], sA[3]));
    if (hb) tm = fmaxf(tm, fmaxf(fmaxf(sB[0], sB[1]), fmaxf(sB[2], sB[3])));
    tm = fmaxf(tm, __shfl_xor(tm, 16));
    tm = fmaxf(tm, __shfl_xor(tm, 32));
    // defer-max: only rescale when the running max actually grows past THR
    if (!__all(tm - m_run <= 8.0f)) {
      const float m_new = fmaxf(m_run, tm);
      const float alpha = __expf(m_run - m_new);
      float aacc[4];
#pragma unroll
      for (int r = 0; r < 4; ++r) aacc[r] = __shfl(alpha, 4 * g + r);
#pragma unroll
      for (int ht = 0; ht < 16; ++ht) {
        acc[ht][0] *= aacc[0]; acc[ht][1] *= aacc[1];
        acc[ht][2] *= aacc[2]; acc[ht][3] *= aacc[3];
      }
      l_run *= alpha;
      m_run = m_new;
    }
    float pA[4], pB[4];
    float ls = 0.f;
#pragma unroll
    for (int r = 0; r < 4; ++r) { pA[r] = __expf(sA[r] - m_run); ls += pA[r]; }
#pragma unroll
    for (int r = 0; r < 4; ++r) { pB[r] = hb ? __expf(sB[r] - m_run) : 0.f; ls += pB[r]; }
    ls += __shfl_xor(ls, 16);
    ls += __shfl_xor(ls, 32);
    l_run += ls;
    // redistribute P^T (D-layout) into PV A-fragment layout
    bf16x8 paf;
#pragma unroll
    for (int j = 0; j < 8; ++j) {
      const int srcl = ((2 * (g & 1) + (j >> 2)) << 4) + c;
      float va = __shfl(pA[j & 3], srcl);
      float vb = __shfl(pB[j & 3], srcl);
      float pv = (g < 2) ? va : vb;
      paf[j] = (short)f2bf(pv);
    }
#pragma unroll
    for (int ht = 0; ht < 16; ++ht) {
      const int h = ht * 16 + c;
      const int slot = (g ^ ((c >> 1) & 3)) * 8;
      bf16x8 vf = *reinterpret_cast<const bf16x8*>(&lV[bi][h * 32 + slot]);
      acc[ht] = mfma16(paf, vf, acc[ht]);
    }
    __syncthreads();  // buf[bi] reads done; staging of buf[bi^1] drained
  }

  const float inv = 1.0f / l_run;
  float ia[4];
#pragma unroll
  for (int r = 0; r < 4; ++r) ia[r] = __shfl(inv, 4 * g + r);
#pragma unroll
  for (int ht = 0; ht < 16; ++ht) {
#pragma unroll
    for (int r = 0; r < 4; ++r) {
      size_t o = ((size_t)((b * 1024 + qbase + 4 * g + r) * 8 + n)) * 256 + ht * 16 + c;
      enc[o] = f2bf(acc[ht][r] * ia[r]);
    }
  }
}

extern "C" void kernel_launch(void* const* d_in, const int* in_sizes, int n_in,
                              void* d_out, int out_size, void* d_ws, size_t ws_size,
                              hipStream_t stream) {
  const float* x0 = (const float*)d_in[0];
  const float* x1 = (const float*)d_in[1];
  const float* wq0 = (const float*)d_in[2];
  const float* wkv0 = (const float*)d_in[3];
  const float* wo0 = (const float*)d_in[4];
  const float* wq1 = (const float*)d_in[5];
  const float* wkv1 = (const float*)d_in[6];
  const float* wo1 = (const float*)d_in[7];
  const int* pos = (const int*)d_in[8];
  float* out = (float*)d_out;

  float* out0 = out;                    // 4*768*2048
  float* out1 = out + 6291456;          // 4*256*1024
  float* k_out = out + 7340032;         // 4*1024*256
  float* v_out = out + 8388608;         // 4*1024*256

  char* ws = (char*)d_ws;
  size_t off = 0;
  auto alloc = [&](size_t bytes) {
    char* p = ws + off;
    off += (bytes + 255) & ~(size_t)255;
    return p;
  };
  US* x0b   = (US*)alloc(6291456ull * 2);
  US* x1b   = (US*)alloc(1048576ull * 2);
  US* btq0  = (US*)alloc(2048ull * 2048 * 2);   // btq0+btkv0 contiguous: [2560][2048]
  US* btkv0 = (US*)alloc(512ull * 2048 * 2);
  US* btq1  = (US*)alloc(2048ull * 1024 * 2);   // btq1+btkv1 contiguous: [2560][1024]
  US* btkv1 = (US*)alloc(512ull * 1024 * 2);
  US* bto0  = (US*)alloc(2048ull * 2048 * 2);
  US* bto1  = (US*)alloc(1024ull * 2048 * 2);
  float* q_raw  = (float*)alloc(8388608ull * 4);
  float* kv_raw = (float*)alloc(2097152ull * 4);
  US* q_bf = (US*)alloc(8388608ull * 2);
  US* k_bf = (US*)alloc(1048576ull * 2);
  US* vt   = (US*)alloc(1048576ull * 2 + 256);
  US* enc  = (US*)alloc(8388608ull * 2);
  (void)btkv0; (void)btkv1;

  // phase 1: casts + weight packs
  k_cast<<<6144, 256, 0, stream>>>(x0, x0b, 1572864);
  k_cast<<<1024, 256, 0, stream>>>(x1, x1b, 262144);
  k_tpack<<<dim3(8, 64, 8), dim3(32, 8), 0, stream>>>(wq0, btq0, 2048, 256, 2048L * 256, 256L * 2048);
  k_tpack<<<dim3(8, 64, 2), dim3(32, 8), 0, stream>>>(wkv0, btkv0, 2048, 256, 2048L * 256, 256L * 2048);
  k_tpack<<<dim3(8, 32, 8), dim3(32, 8), 0, stream>>>(wq1, btq1, 1024, 256, 1024L * 256, 256L * 1024);
  k_tpack<<<dim3(8, 32, 2), dim3(32, 8), 0, stream>>>(wkv1, btkv1, 1024, 256, 1024L * 256, 256L * 1024);
  k_tpack<<<dim3(64, 64, 1), dim3(32, 8), 0, stream>>>(wo0, bto0, 2048, 2048, 0, 0);
  k_tpack<<<dim3(32, 64, 1), dim3(32, 8), 0, stream>>>(wo1, bto1, 2048, 1024, 0, 0);

  // phase 2: fused QKV projection GEMMs (N=2560 = 2048 q + 512 kv)
  k_gemm_qkv<1><<<dim3(20, 24), 256, 0, stream>>>(x0b, btq0, q_raw, kv_raw, 3072, 2048);
  k_gemm_qkv<2><<<dim3(20, 8), 256, 0, stream>>>(x1b, btq1, q_raw, kv_raw, 1024, 1024);

  // phase 3: RoPE + V transpose (also emits k, v fp32 outputs)
  k_rope<<<4096, 256, 0, stream>>>(q_raw, kv_raw, pos, q_bf, k_bf, k_out);
  k_vtrans<<<dim3(32, 8, 4), dim3(32, 8), 0, stream>>>(kv_raw, v_out, vt);

  // phase 4: causal flash attention (work-rank paired blocks, 4 heads/block)
  k_attn<<<512, 256, 0, stream>>>(q_bf, k_bf, vt, enc);

  // phase 5: fused output GEMMs
  k_gemm_out<<<dim3(16, 32), 256, 0, stream>>>(enc, bto0, bto1, out0, out1);
}